// Round 6
// baseline (1681.604 us; speedup 1.0000x reference)
//
#include <hip/hip_runtime.h>
#include <math.h>

typedef _Float16 f16;
typedef _Float16 f16x8 __attribute__((ext_vector_type(8)));
typedef float f32x4 __attribute__((ext_vector_type(4)));

__device__ __forceinline__ float sigmoidf_(float x) { return 1.0f / (1.0f + expf(-x)); }

#define NB 8  // batch

// XCD-chunked decode: physical slot p lands on XCD p%8; each XCD gets a contiguous
// m-chunk; nt (jt/ntile) passes iterate over the chunk (nt-outer within chunk).
__device__ __forceinline__ void decode_swz(int p, int Mtiles, int& mtile, int& nt) {
  if ((Mtiles & 7) == 0) {
    int mch = Mtiles >> 3;
    int c = p & 7, inner = p >> 3;
    nt = inner / mch;
    mtile = c * mch + (inner - nt * mch);
  } else {
    mtile = p % Mtiles;
    nt = p / Mtiles;
  }
}

// ---------------- staging: NCHW f32 -> channel-blocked NHWC f16 ----------------------
// out layout: (B, Cpad/32, S+2p, S+2p, 32), interior at [y+pad][x+pad].
// A pixel row is contiguous at 64 B/px -> MFMA A-fragments become wave-contiguous.
__global__ void k_nchw2nhwc(const float* __restrict__ in, f16* __restrict__ out,
                            int C, int S, int Cpad, int coff, int Wp, int pad) {
  __shared__ float tile[16][17];
  int xt = blockIdx.x;          // x tile
  int ct = blockIdx.y;          // c tile
  int by = blockIdx.z;          // b*S + y
  int b = by / S, y = by % S;
  int x0 = xt * 16, c0 = ct * 16;
  int tx = threadIdx.x & 15, tc = threadIdx.x >> 4;
  float v = 0.f;
  if (c0 + tc < C && x0 + tx < S)
    v = in[(((size_t)b * C + c0 + tc) * S + y) * S + x0 + tx];
  tile[tc][tx] = v;
  __syncthreads();
  int tcc = threadIdx.x & 15;   // channel within tile (fastest)
  int txx = threadIdx.x >> 4;   // x within tile
  if (c0 + tcc < C && x0 + txx < S) {
    int c = coff + c0 + tcc;
    out[((((size_t)b * (Cpad >> 5) + (c >> 5)) * Wp + (y + pad)) * Wp + (x0 + txx + pad)) * 32
        + (c & 31)] = (f16)tile[tcc][txx];
  }
}

// ---------------- weight re-layouts (pads written as zero) ---------------------------
// lstm weights -> Wl[kk][g][jb][cb][16 j][32 ch]: B-fragment = contiguous 1KB.
__global__ void k_wlstm(const float* __restrict__ w, f16* __restrict__ wt,
                        int CH, int CH2, int Jpad, int Cpad) {
  int idx = blockIdx.x * blockDim.x + threadIdx.x;
  int JB16 = Jpad >> 4, KBL = Cpad >> 5;
  int total = 9 * 4 * JB16 * KBL * 512;
  if (idx >= total) return;
  int e = idx & 31;
  int jj = (idx >> 5) & 15;
  int t = idx >> 9;
  int cb = t % KBL; t /= KBL;
  int jb = t % JB16; t /= JB16;
  int g = t & 3; int kk = t >> 2;
  int j = jb * 16 + jj, ci = cb * 32 + e;
  float v = 0.f;
  if (j < CH && ci < CH2)
    v = w[((size_t)(g * CH + j) * CH2 + ci) * 9 + kk];
  wt[idx] = (f16)v;
}

// summary weights -> Ws[kk][nb][cb][16 co][32 ch]
__global__ void k_wsum(const float* __restrict__ w, f16* __restrict__ wt,
                       int C8, int C, int Npad, int Cpad) {
  int idx = blockIdx.x * blockDim.x + threadIdx.x;
  int NB16 = Npad >> 4, KBX = Cpad >> 5;
  int total = 9 * NB16 * KBX * 512;
  if (idx >= total) return;
  int e = idx & 31;
  int nn = (idx >> 5) & 15;
  int t = idx >> 9;
  int cb = t % KBX; t /= KBX;
  int nb = t % NB16; int kk = t / NB16;
  int co = nb * 16 + nn, ci = cb * 32 + e;
  float v = 0.f;
  if (co < C8 && ci < C)
    v = w[((size_t)co * C + ci) * 9 + kk];
  wt[idx] = (f16)v;
}

// ---------------- summary conv GEMM: 4 waves x (32m x 64n), no LDS, no barriers ------
// All loads are wave-contiguous 1KB (channel-blocked A, fragment-blocked W).
__global__ void __launch_bounds__(256)
k_conv_gemm(const f16* __restrict__ A,     // (B,KBX,Sp,Sp,32) pad1
            const f16* __restrict__ Wt,    // [kk][nb][cb][16][32]
            const float* __restrict__ bias,
            f16* __restrict__ D,           // (B,KBL,Sp,Sp,32) pad1, channels [0,C8)
            int S, int lS, int CpadX, int CpadL, int C8, int Npad, int M) {
  int w = threadIdx.x >> 6;
  int lane = threadIdx.x & 63;
  int quad = lane >> 4, r = lane & 15;
  int KBX = CpadX >> 5, KBL = CpadL >> 5, NB16 = Npad >> 4;
  int Mt = (M + 127) >> 7;
  int mtile, ntile;
  decode_swz(blockIdx.x, Mt, mtile, ntile);
  int nb0 = ntile * 4;
  int Sp = S + 2;
  size_t pbase[2];
#pragma unroll
  for (int s = 0; s < 2; s++) {
    int m = mtile * 128 + w * 32 + s * 16 + r;
    if (m >= M) m = M - 1;
    int b = m >> (2 * lS);
    int rem = m & ((1 << (2 * lS)) - 1);
    int y = rem >> lS, x = rem & ((1 << lS) - 1);
    pbase[s] = (((size_t)b * KBX * Sp + y) * Sp + x) * 32 + quad * 8;
  }
  size_t wlane = ((size_t)r << 5) + quad * 8;
  size_t tstep = ((size_t)KBX) << 9;
  f32x4 acc[2][4] = {};
  int T = 9 * KBX;
  int cb = 0, kk = 0;

#define CG_LOAD(AF, BF) do { \
    int ky_ = kk / 3, kx_ = kk - 3 * ky_; \
    size_t aoff_ = ((size_t)cb * Sp * Sp + ky_ * Sp + kx_) * 32; \
    size_t wb_ = (((size_t)(kk * NB16 + nb0) * KBX + cb) << 9) + wlane; \
    AF[0] = *(const f16x8*)(A + pbase[0] + aoff_); \
    AF[1] = *(const f16x8*)(A + pbase[1] + aoff_); \
    _Pragma("unroll") for (int t_ = 0; t_ < 4; t_++) \
      BF[t_] = *(const f16x8*)(Wt + wb_ + (size_t)t_ * tstep); \
  } while (0)
#define CG_ADV() do { kk++; if (kk == 9) { kk = 0; cb++; } } while (0)
#define CG_MF(AF, BF) do { \
    _Pragma("unroll") for (int s_ = 0; s_ < 2; s_++) \
    _Pragma("unroll") for (int t_ = 0; t_ < 4; t_++) \
      acc[s_][t_] = __builtin_amdgcn_mfma_f32_16x16x32_f16(AF[s_], BF[t_], acc[s_][t_], 0, 0, 0); \
  } while (0)

  {
    f16x8 a0[2], b0[4], a1[2], b1[4];
    CG_LOAD(a0, b0); CG_ADV();
    int rem = T - 1;
    while (rem >= 2) {
      CG_LOAD(a1, b1); CG_ADV();
      CG_MF(a0, b0);
      CG_LOAD(a0, b0); CG_ADV();
      CG_MF(a1, b1);
      rem -= 2;
    }
    if (rem == 1) { CG_LOAD(a1, b1); CG_MF(a0, b0); CG_MF(a1, b1); }
    else { CG_MF(a0, b0); }
  }
#undef CG_LOAD
#undef CG_ADV
#undef CG_MF

  // epilogue: wave w writes its 32 m-rows
#pragma unroll
  for (int s = 0; s < 2; s++) {
#pragma unroll
    for (int i = 0; i < 4; i++) {
      int m = mtile * 128 + w * 32 + s * 16 + quad * 4 + i;
      if (m >= M) continue;
      int b = m >> (2 * lS);
      int rem = m & ((1 << (2 * lS)) - 1);
      int y = rem >> lS, x = rem & ((1 << lS) - 1);
#pragma unroll
      for (int t = 0; t < 4; t++) {
        int co = (nb0 + t) * 16 + r;
        if (co < C8) {
          float v = acc[s][t][i] + bias[co];
          D[((((size_t)b * KBL + (co >> 5)) * Sp + (y + 1)) * Sp + (x + 1)) * 32 + (co & 31)]
              = (f16)fmaxf(v, 0.f);
        }
      }
    }
  }
}

// ---------------- LSTM conv GEMM: 4 waves x (32m x 4g x 16j), fused gates ------------
__global__ void __launch_bounds__(256)
k_lstm_gemm(const f16* __restrict__ A,     // (B,KBL,Sp,Sp,32) staged lstm_in
            const f16* __restrict__ Wt,    // [kk][g][jb][cb][16][32]
            const float* __restrict__ lb,  // (4CH)
            const float* __restrict__ cprev,  // (B,CH,S,S) f32
            float* __restrict__ hout, float* __restrict__ cout,
            int S, int lS, int CpadL, int CH, int Jpad, int M) {
  int w = threadIdx.x >> 6;
  int lane = threadIdx.x & 63;
  int quad = lane >> 4, r = lane & 15;
  int KBL = CpadL >> 5, JB16 = Jpad >> 4;
  int Mt = (M + 127) >> 7;
  int mtile, jt;
  decode_swz(blockIdx.x, Mt, mtile, jt);
  int Sp = S + 2;
  size_t pbase[2];
#pragma unroll
  for (int s = 0; s < 2; s++) {
    int m = mtile * 128 + w * 32 + s * 16 + r;
    if (m >= M) m = M - 1;
    int b = m >> (2 * lS);
    int rem = m & ((1 << (2 * lS)) - 1);
    int y = rem >> lS, x = rem & ((1 << lS) - 1);
    pbase[s] = (((size_t)b * KBL * Sp + y) * Sp + x) * 32 + quad * 8;
  }
  size_t wlane = ((size_t)r << 5) + quad * 8;
  size_t gstep = ((size_t)JB16 * KBL) << 9;
  f32x4 acc[2][4] = {};  // [msub][gate]
  int T = 9 * KBL;
  int cb = 0, kk = 0;

#define LG_LOAD(AF, BF) do { \
    int ky_ = kk / 3, kx_ = kk - 3 * ky_; \
    size_t aoff_ = ((size_t)cb * Sp * Sp + ky_ * Sp + kx_) * 32; \
    size_t wb_ = (((size_t)(kk * 4 * JB16 + jt) * KBL + cb) << 9) + wlane; \
    AF[0] = *(const f16x8*)(A + pbase[0] + aoff_); \
    AF[1] = *(const f16x8*)(A + pbase[1] + aoff_); \
    _Pragma("unroll") for (int g_ = 0; g_ < 4; g_++) \
      BF[g_] = *(const f16x8*)(Wt + wb_ + (size_t)g_ * gstep); \
  } while (0)
#define LG_ADV() do { kk++; if (kk == 9) { kk = 0; cb++; } } while (0)
#define LG_MF(AF, BF) do { \
    _Pragma("unroll") for (int s_ = 0; s_ < 2; s_++) \
    _Pragma("unroll") for (int g_ = 0; g_ < 4; g_++) \
      acc[s_][g_] = __builtin_amdgcn_mfma_f32_16x16x32_f16(AF[s_], BF[g_], acc[s_][g_], 0, 0, 0); \
  } while (0)

  {
    f16x8 a0[2], b0[4], a1[2], b1[4];
    LG_LOAD(a0, b0); LG_ADV();
    int rem = T - 1;
    while (rem >= 2) {
      LG_LOAD(a1, b1); LG_ADV();
      LG_MF(a0, b0);
      LG_LOAD(a0, b0); LG_ADV();
      LG_MF(a1, b1);
      rem -= 2;
    }
    if (rem == 1) { LG_LOAD(a1, b1); LG_MF(a0, b0); LG_MF(a1, b1); }
    else { LG_MF(a0, b0); }
  }
#undef LG_LOAD
#undef LG_ADV
#undef LG_MF

  int j = jt * 16 + r;
  if (j >= CH) return;
  float bi = lb[j];
  float bf_ = lb[CH + j];
  float bo = lb[2 * CH + j];
  float bg = lb[3 * CH + j];
#pragma unroll
  for (int s = 0; s < 2; s++) {
#pragma unroll
    for (int i = 0; i < 4; i++) {
      int m = mtile * 128 + w * 32 + s * 16 + quad * 4 + i;
      if (m >= M) continue;
      int b = m >> (2 * lS);
      int rem = m & ((1 << (2 * lS)) - 1);
      int y = rem >> lS, x = rem & ((1 << lS) - 1);
      size_t o = (((size_t)b * CH + j) * S + y) * S + x;
      float ig = sigmoidf_(acc[s][0][i] + bi);
      float fg = sigmoidf_(acc[s][1][i] + bf_);
      float og = sigmoidf_(acc[s][2][i] + bo);
      float gg = tanhf(acc[s][3][i] + bg);
      float cn = fg * cprev[o] + ig * gg;
      hout[o] = og * tanhf(cn);
      cout[o] = cn;
    }
  }
}

// ---------------- correlation (small levels 3-5): f32 exact, f16 copy into staged D --
__global__ void k_corr(const float* __restrict__ f1, const float* __restrict__ f2,
                       float* __restrict__ corr_out, f16* __restrict__ D,
                       int C, int S, int CpadL, int C8) {
  int idx = blockIdx.x * blockDim.x + threadIdx.x;
  int total = NB * 49 * S * S;
  if (idx >= total) return;
  int px = idx % S; int t = idx / S;
  int py = t % S; t /= S;
  int d = t % 49; int b = t / 49;
  int qy = py + d / 7 - 3;
  int qx = px + d % 7 - 3;

  float acc = 0.f;
  if (qy >= 0 && qy < S && qx >= 0 && qx < S) {
    const float* p1 = f1 + ((size_t)b * C * S + py) * S + px;
    const float* p2 = f2 + ((size_t)b * C * S + qy) * S + qx;
    size_t cs = (size_t)S * S;
    for (int ci = 0; ci < C; ci++) {
      acc += p1[(size_t)ci * cs] * p2[(size_t)ci * cs];
    }
  }
  float lr = (acc > 0.f) ? acc : 0.01f * acc;
  corr_out[idx] = lr;
  int Sp = S + 2;
  int ch = C8 + d, KBL = CpadL >> 5;
  D[((((size_t)b * KBL + (ch >> 5)) * Sp + (py + 1)) * Sp + (px + 1)) * 32 + (ch & 31)] = (f16)lr;
}

// ---------------- correlation (big levels 0-2): banded MFMA Gram tiles ---------------
// A, A2 channel-blocked -> all loads wave-contiguous.
template<int S>
__global__ void __launch_bounds__(256)
k_corr_mfma(const f16* __restrict__ A,     // (B,KBX,S+2,S+2,32)
            const f16* __restrict__ A2,    // (B,KBX,S+6,S+6,32)
            float* __restrict__ corr_out,  // (B,49,S,S)
            f16* __restrict__ D,           // (B,KBL,S+2,S+2,32), channels [C8,C8+49)
            int C, int CpadL, int C8) {
  constexpr int XT = S / 16;
  constexpr int Sp = S + 2, Sq = S + 6;
  int KBX = C >> 5, KBL = CpadL >> 5;
  int nb = gridDim.x;
  int eb = (blockIdx.x % 8) * (nb / 8) + blockIdx.x / 8;
  int wid = eb * 4 + (threadIdx.x >> 6);
  int lane = threadIdx.x & 63;
  int quad = lane >> 4, r = lane & 15;
  int xt = wid % XT; int t1 = wid / XT;
  int y = t1 % S; int b = t1 / S;
  int x0 = xt * 16;

  size_t baseA = ((((size_t)b * KBX) * Sp + (y + 1)) * Sp + (x0 + r + 1)) * 32 + quad * 8;
  size_t stepA = (size_t)Sp * Sp * 32;
  int xs1 = x0 + 16 + r; if (xs1 > S + 5) xs1 = S + 5;
  size_t off0 = (size_t)(x0 + r) * 32 + quad * 8;
  size_t off1 = (size_t)xs1 * 32 + quad * 8;
  size_t baseB = ((size_t)b * KBX) * Sq * Sq * 32 + (size_t)y * Sq * 32;
  size_t stepB = (size_t)Sq * Sq * 32;

  f32x4 acc[7][2] = {};
  for (int cbi = 0; cbi < KBX; cbi++) {
    f16x8 af = *(const f16x8*)(A + baseA + (size_t)cbi * stepA);
    const f16* pbb = A2 + baseB + (size_t)cbi * stepB;
#pragma unroll
    for (int dyo = 0; dyo < 7; dyo++) {
      const f16* pr = pbb + (size_t)dyo * Sq * 32;
      f16x8 b0 = *(const f16x8*)(pr + off0);
      f16x8 b1 = *(const f16x8*)(pr + off1);
      acc[dyo][0] = __builtin_amdgcn_mfma_f32_16x16x32_f16(af, b0, acc[dyo][0], 0, 0, 0);
      acc[dyo][1] = __builtin_amdgcn_mfma_f32_16x16x32_f16(af, b1, acc[dyo][1], 0, 0, 0);
    }
  }
#pragma unroll
  for (int dyo = 0; dyo < 7; dyo++) {
#pragma unroll
    for (int t = 0; t < 2; t++) {
#pragma unroll
      for (int i = 0; i < 4; i++) {
        int ml = quad * 4 + i;
        int dxo = r - ml + t * 16;
        if (dxo < 0 || dxo > 6) continue;
        float v = acc[dyo][t][i];
        float lr = (v > 0.f) ? v : 0.01f * v;
        int d = dyo * 7 + dxo;
        int x = x0 + ml;
        corr_out[(((size_t)b * 49 + d) * S + y) * S + x] = lr;
        int ch = C8 + d;
        D[((((size_t)b * KBL + (ch >> 5)) * Sp + (y + 1)) * Sp + (x + 1)) * 32 + (ch & 31)]
            = (f16)lr;
      }
    }
  }
}

extern "C" void kernel_launch(void* const* d_in, const int* in_sizes, int n_in,
                              void* d_out, int out_size, void* d_ws, size_t ws_size,
                              hipStream_t stream) {
  (void)in_sizes; (void)n_in; (void)out_size; (void)ws_size;
  static const int CINa[6] = {512, 1024, 512, 256, 256, 256};
  static const int Sa[6]   = {64, 32, 16, 8, 4, 2};
  static const int lSa[6]  = {6, 5, 4, 3, 2, 1};
  static const int CHa[6]  = {113, 177, 113, 81, 81, 81};
  static const int CpadLa[6] = {256, 384, 256, 192, 192, 192};  // 2*CH -> mult of 32
  static const int Jpada[6]  = {128, 192, 128, 96, 96, 96};     // CH -> mult of 16
  const int B = 8;

  size_t h_off[6], c_off[6], corr_off[6];
  size_t off = 0;
  for (int i = 0; i < 6; i++) { h_off[i] = off;    off += (size_t)B * CHa[i] * Sa[i] * Sa[i]; }
  for (int i = 0; i < 6; i++) { c_off[i] = off;    off += (size_t)B * CHa[i] * Sa[i] * Sa[i]; }
  for (int i = 0; i < 6; i++) { corr_off[i] = off; off += (size_t)B * 49 * Sa[i] * Sa[i]; }

  float* out = (float*)d_out;
  char* ws = (char*)d_ws;
  // arena: A (x blocked) 36MB | D (lstm_in blocked) 18MB | Wsum 3MB | Wlstm 6MB |
  //        A2 (xp blocked pad3, levels 0-2) max 40.2MB -> ~103.3MB
  const size_t offA = 0;
  const size_t offD = 37748736;
  const size_t offWs = offD + 18874368;
  const size_t offWl = offWs + 3145728;
  const size_t offA2 = offWl + 6291456;

  for (int i = 0; i < 6; i++) {
    const float* x  = (const float*)d_in[8 * i + 0];
    const float* xp = (const float*)d_in[8 * i + 1];
    const float* h  = (const float*)d_in[8 * i + 2];
    const float* c  = (const float*)d_in[8 * i + 3];
    const float* sw = (const float*)d_in[8 * i + 4];
    const float* sb = (const float*)d_in[8 * i + 5];
    const float* lw = (const float*)d_in[8 * i + 6];
    const float* lb = (const float*)d_in[8 * i + 7];
    int C = CINa[i], S = Sa[i], lS = lSa[i], CH = CHa[i], C8 = C / 8;
    int CH2 = 2 * CH, CpadL = CpadLa[i], Jpad = Jpada[i];
    int Sp = S + 2;
    int Npad = (C8 + 63) / 64 * 64;
    int M = B * S * S;
    int Mt128 = (M + 127) / 128;

    f16* Abuf = (f16*)(ws + offA);
    f16* Dbuf = (f16*)(ws + offD);
    f16* Wsum = (f16*)(ws + offWs);
    f16* Wlstm = (f16*)(ws + offWl);
    f16* A2buf = (f16*)(ws + offA2);

    size_t sizeA = (size_t)B * Sp * Sp * C * 2;
    size_t sizeD = (size_t)B * Sp * Sp * CpadL * 2;
    hipMemsetAsync(Abuf, 0, sizeA, stream);
    hipMemsetAsync(Dbuf, 0, sizeD, stream);

    // x -> A (channel-blocked f16, pad1)
    {
      dim3 g((S + 15) / 16, (C + 15) / 16, B * S);
      k_nchw2nhwc<<<g, 256, 0, stream>>>(x, Abuf, C, S, C, 0, Sp, 1);
    }
    // summary weights (fragment-blocked)
    {
      int tot = 9 * Npad * C;
      k_wsum<<<(tot + 255) / 256, 256, 0, stream>>>(sw, Wsum, C8, C, Npad, C);
    }
    // summary GEMM -> D channels [0, C8)
    {
      k_conv_gemm<<<Mt128 * (Npad / 64), 256, 0, stream>>>(Abuf, Wsum, sb, Dbuf,
                                                           S, lS, C, CpadL, C8, Npad, M);
    }
    // correlation -> d_out (f32) + D channels [C8, C8+49)
    if (i < 3) {
      int Sq = S + 6;
      size_t sizeA2 = (size_t)B * Sq * Sq * C * 2;
      hipMemsetAsync(A2buf, 0, sizeA2, stream);
      {
        dim3 g((S + 15) / 16, (C + 15) / 16, B * S);
        k_nchw2nhwc<<<g, 256, 0, stream>>>(xp, A2buf, C, S, C, 0, Sq, 3);
      }
      int blocks = B * S * (S / 16) / 4;   // one wave per 16-pixel A-tile
      if (i == 0)
        k_corr_mfma<64><<<blocks, 256, 0, stream>>>(Abuf, A2buf, out + corr_off[i], Dbuf,
                                                    C, CpadL, C8);
      else if (i == 1)
        k_corr_mfma<32><<<blocks, 256, 0, stream>>>(Abuf, A2buf, out + corr_off[i], Dbuf,
                                                    C, CpadL, C8);
      else
        k_corr_mfma<16><<<blocks, 256, 0, stream>>>(Abuf, A2buf, out + corr_off[i], Dbuf,
                                                    C, CpadL, C8);
    } else {
      int tot = B * 49 * S * S;
      k_corr<<<(tot + 255) / 256, 256, 0, stream>>>(x, xp, out + corr_off[i], Dbuf,
                                                    C, S, CpadL, C8);
    }
    // h -> D channels [C8+49, 2CH)
    {
      dim3 g((S + 15) / 16, (CH + 15) / 16, B * S);
      k_nchw2nhwc<<<g, 256, 0, stream>>>(h, Dbuf, CH, S, CpadL, C8 + 49, Sp, 1);
    }
    // lstm weights (fragment-blocked)
    {
      int tot = 9 * 4 * Jpad * CpadL;
      k_wlstm<<<(tot + 255) / 256, 256, 0, stream>>>(lw, Wlstm, CH, CH2, Jpad, CpadL);
    }
    // LSTM GEMM + fused gates
    {
      k_lstm_gemm<<<Mt128 * (Jpad / 16), 256, 0, stream>>>(Dbuf, Wlstm, lb, c,
                                                           out + h_off[i], out + c_off[i],
                                                           S, lS, CpadL, CH, Jpad, M);
    }
  }
}